// Round 7
// baseline (416.226 us; speedup 1.0000x reference)
//
#include <hip/hip_runtime.h>
#include <cstdint>
#include <cstddef>

#define M_DIM 4096
#define N_DIM 8192
#define K_DIM 4096

typedef __attribute__((ext_vector_type(4))) int int4v;

// ---------------------------------------------------------------------------
// Pack into MFMA-fragment order (int32 -> int8). R3-verified, byte-identical.
// p = 16-row panel, s = 64-byte kstep, lane l: chunk(p,s) is 1024 B where
// lane l holds row 16p+(l&15), k-bytes s*64 + (l>>4)*16 .. +16.
// ---------------------------------------------------------------------------
__global__ void __launch_bounds__(256) pack_frag(const int* __restrict__ a,
                                                 const int* __restrict__ b,
                                                 unsigned char* __restrict__ pa,
                                                 unsigned char* __restrict__ pb) {
    size_t t = (size_t)blockIdx.x * 256 + threadIdx.x;
    const size_t NA = (size_t)(M_DIM / 16) * (K_DIM / 64) * 64;
    const int* __restrict__ src;
    unsigned char* __restrict__ dst;
    if (t < NA) {
        src = a; dst = pa;
    } else {
        src = b; dst = pb; t -= NA;
    }
    const int l = (int)(t & 63);
    const int s = (int)((t >> 6) & 63);
    const int p = (int)(t >> 12);
    const int* g = src + ((size_t)(16 * p + (l & 15))) * K_DIM + s * 64 + (l >> 4) * 16;
    const int4v* g4 = (const int4v*)g;
    int4v o;
#pragma unroll
    for (int q = 0; q < 4; ++q) {
        int4v v = g4[q];
        o[q] = (v[0] & 0xff) | ((v[1] & 0xff) << 8) | ((v[2] & 0xff) << 16) | (v[3] << 24);
    }
    ((int4v*)dst)[t] = o;
}

// ---------------------------------------------------------------------------
// GEMM: block 256x256, 512 thr = 8 waves, wave tile 64x128 (4 A x 8 B
// panels), mfma_i32_16x16x64_i8, BK=64, LDS double-buffered 2x32 KB.
// KEY CHANGE vs R6: bf fragments in a 4-slot rotating ring; ds_read of
// bf(j+2) is issued BETWEEN the MFMAs consuming bf(j). Ring register reuse
// (WAR) pins the interleave so the LDS pipe services reads concurrently
// with the matrix pipe instead of phase-locked read->MFMA lockstep.
// ---------------------------------------------------------------------------
__device__ inline void async_copy16(const unsigned char* g, unsigned char* l) {
    __builtin_amdgcn_global_load_lds(
        (const __attribute__((address_space(1))) void*)g,
        (__attribute__((address_space(3))) void*)l,
        16, 0, 0);
}

__global__ void __launch_bounds__(512, 2) gemm_i8(const unsigned char* __restrict__ Ap,
                                                  const unsigned char* __restrict__ Bp,
                                                  const _Float16* __restrict__ arow,
                                                  const _Float16* __restrict__ acol,
                                                  _Float16* __restrict__ Cout) {
    __shared__ __align__(16) unsigned char As[2 * 16384];
    __shared__ __align__(16) unsigned char Bs[2 * 16384];

    const int tid  = threadIdx.x;
    const int lane = tid & 63;
    const int wave = tid >> 6;        // 0..7
    const int bn   = blockIdx.x;      // 0..31 (256 cols)
    const int bm   = blockIdx.y;      // 0..15 (256 rows)

    const int pm0 = (wave & 3) * 4;   // A panel base (4 panels = 64 rows)
    const int pn0 = (wave >> 2) * 8;  // B panel base (8 panels = 128 cols)

    // staging: wave w stages A panels {2w,2w+1} and B panels {2w,2w+1}
    const unsigned char* ag[2];
    const unsigned char* bg[2];
    int slo[2];
#pragma unroll
    for (int r = 0; r < 2; ++r) {
        const int p = 2 * wave + r;
        ag[r]  = Ap + (size_t)(bm * 16 + p) * 65536 + lane * 16;
        bg[r]  = Bp + (size_t)(bn * 16 + p) * 65536 + lane * 16;
        slo[r] = p * 1024;  // wave-uniform; HW adds lane*16
    }

    const int a_off = pm0 * 1024 + lane * 16;  // + i*1024
    const int b_off = pn0 * 1024 + lane * 16;  // + j*1024

    int4v acc[4][8];
#pragma unroll
    for (int i = 0; i < 4; ++i)
#pragma unroll
        for (int j = 0; j < 8; ++j) acc[i][j] = (int4v)0;

    const int NT = K_DIM / 64;  // 64

    // prologue: stage T=0 into buffer 0
#pragma unroll
    for (int r = 0; r < 2; ++r) {
        async_copy16(ag[r], As + slo[r]);
        async_copy16(bg[r], Bs + slo[r]);
    }
    __syncthreads();

    for (int T = 0; T < NT; ++T) {
        const int cur = (T & 1) * 16384;
        const int nxt = cur ^ 16384;

        // stage T+1 (async; drained only at the barrier below)
        if (T + 1 < NT) {
            const size_t gko = (size_t)(T + 1) * 1024;
#pragma unroll
            for (int r = 0; r < 2; ++r) {
                async_copy16(ag[r] + gko, As + nxt + slo[r]);
                async_copy16(bg[r] + gko, Bs + nxt + slo[r]);
            }
        }

        const unsigned char* Ac = As + cur;
        const unsigned char* Bc = Bs + cur;

        // head loads: all 4 af + first 2 bf ring slots
        int4v af[4], ring[4];
#pragma unroll
        for (int i = 0; i < 4; ++i)
            af[i] = *(const int4v*)(Ac + a_off + i * 1024);
        ring[0] = *(const int4v*)(Bc + b_off);
        ring[1] = *(const int4v*)(Bc + b_off + 1024);

        // interleaved steady state: read bf(j+2) between MFMAs on bf(j).
        // ring[(j+2)&3] was last consumed at step j-2 -> WAR pins the order.
#pragma unroll
        for (int j = 0; j < 8; ++j) {
            if (j < 6)
                ring[(j + 2) & 3] = *(const int4v*)(Bc + b_off + (j + 2) * 1024);
            const int4v bfj = ring[j & 3];
            acc[0][j] = __builtin_amdgcn_mfma_i32_16x16x64_i8(af[0], bfj, acc[0][j], 0, 0, 0);
            acc[1][j] = __builtin_amdgcn_mfma_i32_16x16x64_i8(af[1], bfj, acc[1][j], 0, 0, 0);
            acc[2][j] = __builtin_amdgcn_mfma_i32_16x16x64_i8(af[2], bfj, acc[2][j], 0, 0, 0);
            acc[3][j] = __builtin_amdgcn_mfma_i32_16x16x64_i8(af[3], bfj, acc[3][j], 0, 0, 0);
        }

        __syncthreads();
    }

    // --- epilogue: C/D layout col=lane&15, row=(lane>>4)*4+reg (verified)
    const int gcol0 = bn * 256 + pn0 * 16 + (lane & 15);
    float ac8[8];
#pragma unroll
    for (int j = 0; j < 8; ++j) ac8[j] = (float)acol[gcol0 + j * 16];

    const size_t grow0 = (size_t)bm * 256 + pm0 * 16 + (lane >> 4) * 4;
#pragma unroll
    for (int i = 0; i < 4; ++i) {
#pragma unroll
        for (int r = 0; r < 4; ++r) {
            const size_t row = grow0 + i * 16 + r;
            const float ar = (float)arow[row];
            _Float16* outp = Cout + row * (size_t)N_DIM + gcol0;
#pragma unroll
            for (int j = 0; j < 8; ++j) {
                float v = (float)acc[i][j][r] * ar * ac8[j];
                outp[j * 16] = (_Float16)v;
            }
        }
    }
}

// ---------------------------------------------------------------------------
extern "C" void kernel_launch(void* const* d_in, const int* in_sizes, int n_in,
                              void* d_out, int out_size, void* d_ws, size_t ws_size,
                              hipStream_t stream) {
    const int* a = (const int*)d_in[0];             // [M,K] int32 (int8 values)
    const int* b = (const int*)d_in[1];             // [N,K] int32 (int8 values)
    const _Float16* ar = (const _Float16*)d_in[2];  // [M] fp16
    const _Float16* ac = (const _Float16*)d_in[3];  // [N] fp16
    _Float16* out = (_Float16*)d_out;               // [M,N] fp16

    unsigned char* pa = (unsigned char*)d_ws;        // 16 MB
    unsigned char* pb = pa + (size_t)M_DIM * K_DIM;  // 32 MB

    const size_t total_frag = (size_t)(M_DIM / 16 + N_DIM / 16) * (K_DIM / 64) * 64;
    pack_frag<<<(int)(total_frag / 256), 256, 0, stream>>>(a, b, pa, pb);

    dim3 grid(N_DIM / 256, M_DIM / 256);
    gemm_i8<<<grid, 512, 0, stream>>>(pa, pb, ar, ac, out);
}

// Round 8
// 373.978 us; speedup vs baseline: 1.1130x; 1.1130x over previous
//
#include <hip/hip_runtime.h>
#include <cstdint>
#include <cstddef>

#define M_DIM 4096
#define N_DIM 8192
#define K_DIM 4096

typedef __attribute__((ext_vector_type(4))) int int4v;

// ---------------------------------------------------------------------------
// Pack into MFMA-fragment order (int32 -> int8). R3-verified, byte-identical.
// p = 16-row panel, s = 64-byte kstep, lane l: chunk(p,s) is 1024 B where
// lane l holds row 16p+(l&15), k-bytes s*64 + (l>>4)*16 .. +16.
// ---------------------------------------------------------------------------
__global__ void __launch_bounds__(256) pack_frag(const int* __restrict__ a,
                                                 const int* __restrict__ b,
                                                 unsigned char* __restrict__ pa,
                                                 unsigned char* __restrict__ pb) {
    size_t t = (size_t)blockIdx.x * 256 + threadIdx.x;
    const size_t NA = (size_t)(M_DIM / 16) * (K_DIM / 64) * 64;
    const int* __restrict__ src;
    unsigned char* __restrict__ dst;
    if (t < NA) {
        src = a; dst = pa;
    } else {
        src = b; dst = pb; t -= NA;
    }
    const int l = (int)(t & 63);
    const int s = (int)((t >> 6) & 63);
    const int p = (int)(t >> 12);
    const int* g = src + ((size_t)(16 * p + (l & 15))) * K_DIM + s * 64 + (l >> 4) * 16;
    const int4v* g4 = (const int4v*)g;
    int4v o;
#pragma unroll
    for (int q = 0; q < 4; ++q) {
        int4v v = g4[q];
        o[q] = (v[0] & 0xff) | ((v[1] & 0xff) << 8) | ((v[2] & 0xff) << 16) | (v[3] << 24);
    }
    ((int4v*)dst)[t] = o;
}

// ---------------------------------------------------------------------------
// GEMM: block 256x256, 512 thr = 8 waves, wave tile 64x128 (4 A x 8 B
// panels), mfma_i32_16x16x64_i8 (verified layouts), BK=64.
// R8 change vs R6: QUAD-buffered LDS (4 x 32 KB), ONE barrier per TWO
// K-iters. Stages for T+2 / T+3 are issued at the window top, then two
// full compute iterations run before the barrier's vmcnt drain — and with
// half as many barriers, waves drift within a ~2600-cy window so LDS-read
// bursts of some waves overlap MFMA bursts of others (breaks the
// phase-lock that held R6 at 50% matrix-pipe busy).
// Fragment reads are left in bulk per iter for the compiler to schedule
// (R7 showed source-pinned interleave defeats waitcnt scheduling).
// ---------------------------------------------------------------------------
__device__ inline void async_copy16(const unsigned char* g, unsigned char* l) {
    __builtin_amdgcn_global_load_lds(
        (const __attribute__((address_space(1))) void*)g,
        (__attribute__((address_space(3))) void*)l,
        16, 0, 0);
}

__global__ void __launch_bounds__(512, 2) gemm_i8(const unsigned char* __restrict__ Ap,
                                                  const unsigned char* __restrict__ Bp,
                                                  const _Float16* __restrict__ arow,
                                                  const _Float16* __restrict__ acol,
                                                  _Float16* __restrict__ Cout) {
    __shared__ __align__(16) unsigned char As[4 * 16384];
    __shared__ __align__(16) unsigned char Bs[4 * 16384];

    const int tid  = threadIdx.x;
    const int lane = tid & 63;
    const int wave = tid >> 6;        // 0..7
    const int bn   = blockIdx.x;      // 0..31 (256 cols)
    const int bm   = blockIdx.y;      // 0..15 (256 rows)

    const int pm0 = (wave & 3) * 4;   // A panel base (4 panels = 64 rows)
    const int pn0 = (wave >> 2) * 8;  // B panel base (8 panels = 128 cols)

    // staging: wave w stages A panels {2w,2w+1} and B panels {2w,2w+1}
    const unsigned char* ag[2];
    const unsigned char* bg[2];
    int slo[2];
#pragma unroll
    for (int r = 0; r < 2; ++r) {
        const int p = 2 * wave + r;
        ag[r]  = Ap + (size_t)(bm * 16 + p) * 65536 + lane * 16;
        bg[r]  = Bp + (size_t)(bn * 16 + p) * 65536 + lane * 16;
        slo[r] = p * 1024;  // wave-uniform; HW adds lane*16
    }

    const int a_off = pm0 * 1024 + lane * 16;  // + i*1024
    const int b_off = pn0 * 1024 + lane * 16;  // + j*1024

    int4v acc[4][8];
#pragma unroll
    for (int i = 0; i < 4; ++i)
#pragma unroll
        for (int j = 0; j < 8; ++j) acc[i][j] = (int4v)0;

    const int NT = K_DIM / 64;  // 64, even

    // prologue: stage T=0 -> buf0, T=1 -> buf1
#pragma unroll
    for (int r = 0; r < 2; ++r) {
        async_copy16(ag[r], As + slo[r]);
        async_copy16(bg[r], Bs + slo[r]);
        async_copy16(ag[r] + 1024, As + 16384 + slo[r]);
        async_copy16(bg[r] + 1024, Bs + 16384 + slo[r]);
    }
    __syncthreads();

    for (int T = 0; T < NT; T += 2) {
        // stage T+2, T+3 into their ring buffers (drained at the barrier
        // below, after TWO full compute iterations)
        if (T + 2 < NT) {
            const size_t gko = (size_t)(T + 2) * 1024;
            const int buf = ((T + 2) & 3) * 16384;
#pragma unroll
            for (int r = 0; r < 2; ++r) {
                async_copy16(ag[r] + gko, As + buf + slo[r]);
                async_copy16(bg[r] + gko, Bs + buf + slo[r]);
            }
            const size_t gko3 = gko + 1024;
            const int buf3 = ((T + 3) & 3) * 16384;
#pragma unroll
            for (int r = 0; r < 2; ++r) {
                async_copy16(ag[r] + gko3, As + buf3 + slo[r]);
                async_copy16(bg[r] + gko3, Bs + buf3 + slo[r]);
            }
        }

        // two compute iterations; bulk reads per iter, compiler-scheduled
#pragma unroll
        for (int u = 0; u < 2; ++u) {
            const int cur = ((T + u) & 3) * 16384;
            const unsigned char* Ac = As + cur;
            const unsigned char* Bc = Bs + cur;

            int4v af[4], bf[8];
#pragma unroll
            for (int i = 0; i < 4; ++i)
                af[i] = *(const int4v*)(Ac + a_off + i * 1024);
#pragma unroll
            for (int j = 0; j < 8; ++j)
                bf[j] = *(const int4v*)(Bc + b_off + j * 1024);

#pragma unroll
            for (int i = 0; i < 4; ++i)
#pragma unroll
                for (int j = 0; j < 8; ++j)
                    acc[i][j] = __builtin_amdgcn_mfma_i32_16x16x64_i8(af[i], bf[j],
                                                                      acc[i][j], 0, 0, 0);
        }

        __syncthreads();
    }

    // --- epilogue: C/D layout col=lane&15, row=(lane>>4)*4+reg (verified)
    const int gcol0 = bn * 256 + pn0 * 16 + (lane & 15);
    float ac8[8];
#pragma unroll
    for (int j = 0; j < 8; ++j) ac8[j] = (float)acol[gcol0 + j * 16];

    const size_t grow0 = (size_t)bm * 256 + pm0 * 16 + (lane >> 4) * 4;
#pragma unroll
    for (int i = 0; i < 4; ++i) {
#pragma unroll
        for (int r = 0; r < 4; ++r) {
            const size_t row = grow0 + i * 16 + r;
            const float ar = (float)arow[row];
            _Float16* outp = Cout + row * (size_t)N_DIM + gcol0;
#pragma unroll
            for (int j = 0; j < 8; ++j) {
                float v = (float)acc[i][j][r] * ar * ac8[j];
                outp[j * 16] = (_Float16)v;
            }
        }
    }
}

// ---------------------------------------------------------------------------
extern "C" void kernel_launch(void* const* d_in, const int* in_sizes, int n_in,
                              void* d_out, int out_size, void* d_ws, size_t ws_size,
                              hipStream_t stream) {
    const int* a = (const int*)d_in[0];             // [M,K] int32 (int8 values)
    const int* b = (const int*)d_in[1];             // [N,K] int32 (int8 values)
    const _Float16* ar = (const _Float16*)d_in[2];  // [M] fp16
    const _Float16* ac = (const _Float16*)d_in[3];  // [N] fp16
    _Float16* out = (_Float16*)d_out;               // [M,N] fp16

    unsigned char* pa = (unsigned char*)d_ws;        // 16 MB
    unsigned char* pb = pa + (size_t)M_DIM * K_DIM;  // 32 MB

    const size_t total_frag = (size_t)(M_DIM / 16 + N_DIM / 16) * (K_DIM / 64) * 64;
    pack_frag<<<(int)(total_frag / 256), 256, 0, stream>>>(a, b, pa, pb);

    dim3 grid(N_DIM / 256, M_DIM / 256);
    gemm_i8<<<grid, 512, 0, stream>>>(pa, pb, ar, ac, out);
}